// Round 2
// baseline (157.410 us; speedup 1.0000x reference)
//
#include <hip/hip_runtime.h>

#define HH 1024
#define WW 1024
#define NB 16
#define TR 8                        // output rows per block
#define NBLK (NB * (HH / TR))       // 2048 blocks
#define NELEM ((long long)NB * HH * WW)

// Build an 8-float stencil window [c0-2 .. c0+5] for global row gy, directly
// from global memory (no LDS). One row base address; the three loads fold to
// imm offsets -8 / 0 / +16. Rows outside [0,HH) are the reference's zero pad.
// Values (and zero-fix order) are bit-identical to the previous LDS path.
__device__ __forceinline__ void gwin(const float* __restrict__ ybase, int gy,
                                     int c0, bool ledge, bool redge, float w[8]) {
    if (gy >= 0 && gy < HH) {                     // block-uniform branch
        const float* r = ybase + gy * WW;
        float2 L = *(const float2*)(r + (ledge ? c0 : c0 - 2));
        float4 M = *(const float4*)(r + c0);
        float2 R = *(const float2*)(r + (redge ? c0 : c0 + 4));
        if (ledge) { L.x = 0.f; L.y = 0.f; }
        if (redge) { R.x = 0.f; R.y = 0.f; }
        w[0]=L.x; w[1]=L.y; w[2]=M.x; w[3]=M.y; w[4]=M.z; w[5]=M.w; w[6]=R.x; w[7]=R.y;
    } else {
#pragma unroll
        for (int i = 0; i < 8; ++i) w[i] = 0.f;
    }
}

// Per-output-row math: identical op ordering to the previous kernel so the
// per-thread accumulation stays bit-identical (absmax 0.0 preserved).
__device__ __forceinline__ void row4(const float A[8], const float B[8],
                                     const float C[8], const float4 t4,
                                     float& sum) {
    const float tt[4] = {t4.x, t4.y, t4.z, t4.w};
#pragma unroll
    for (int j = 0; j < 4; ++j) {
        const float c = B[j + 2];
        // max|c-nb| = max(max(nb)-c, c-min(nb)); folds to v_max3/v_min3.
        const float mxA = fmaxf(fmaxf(A[j], A[j + 2]), A[j + 4]);
        const float mxB = fmaxf(B[j], B[j + 4]);
        const float mxC = fmaxf(fmaxf(C[j], C[j + 2]), C[j + 4]);
        const float mx  = fmaxf(fmaxf(mxA, mxB), mxC);
        const float mnA = fminf(fminf(A[j], A[j + 2]), A[j + 4]);
        const float mnB = fminf(B[j], B[j + 4]);
        const float mnC = fminf(fminf(C[j], C[j + 2]), C[j + 4]);
        const float mn  = fminf(fminf(mnA, mnB), mnC);
        const float w   = fmaxf(mx - c, c - mn);

        // log1p(-c) == log(1-c) exactly in fp32 for c in [0.5,1) (Sterbenz);
        // -100 clamp covers c -> 1 / c == 0.
        const float lp  = fmaxf(__logf(c), -100.f);
        const float l1p = fmaxf(__logf(1.f - c), -100.f);
        const float th  = (c >= 0.5f) ? c : 0.f;
        sum += w * th - l1p - tt[j] * (lp - l1p);
    }
}

// No data LDS: stencil windows roll through registers, two parity pipelines
// (row k consumes rows k-2,k,k+2 -> even/odd rows are independent streams).
// Each of the 12 involved y_pred rows has its window built exactly once.
__global__ __launch_bounds__(256, 4) void closs_main(const float* __restrict__ yt,
                                                     const float* __restrict__ yp,
                                                     float* __restrict__ partial) {
    const int bid  = blockIdx.x;
    const int img  = bid >> 7;          // 128 tiles per image
    const int tile = bid & 127;
    const int y0   = tile * TR;
    const int tid  = threadIdx.x;
    const int c0   = tid << 2;          // 4 columns per thread

    const bool ledge = (tid == 0);
    const bool redge = (tid == 255);

    const float* __restrict__ ybase = yp + (long long)img * (HH * WW);
    const float* __restrict__ tbase = yt + ((long long)img * HH + y0) * WW;

    // Prime both parity pipelines: even rows {y0-2, y0}, odd rows {y0-1, y0+1}.
    float Ae[8], Be[8], Ce[8], Ao[8], Bo[8], Co[8];
    gwin(ybase, y0 - 2, c0, ledge, redge, Ae);
    gwin(ybase, y0,     c0, ledge, redge, Be);
    gwin(ybase, y0 - 1, c0, ledge, redge, Ao);
    gwin(ybase, y0 + 1, c0, ledge, redge, Bo);

    float sum = 0.f;
#pragma unroll
    for (int k = 0; k < TR; ++k) {      // ascending k: accumulation order kept
        const float4 t4 = *(const float4*)(tbase + k * WW + c0);
        if ((k & 1) == 0) {
            gwin(ybase, y0 + k + 2, c0, ledge, redge, Ce);
            row4(Ae, Be, Ce, t4, sum);
#pragma unroll
            for (int i = 0; i < 8; ++i) { Ae[i] = Be[i]; Be[i] = Ce[i]; }
        } else {
            gwin(ybase, y0 + k + 2, c0, ledge, redge, Co);
            row4(Ao, Bo, Co, t4, sum);
#pragma unroll
            for (int i = 0; i < 8; ++i) { Ao[i] = Bo[i]; Bo[i] = Co[i]; }
        }
    }

    // Block reduction -> one partial write (no atomics: R4 proved 16K
    // same-address atomicAdds serialize to ~215 us).
    for (int o = 32; o > 0; o >>= 1) sum += __shfl_down(sum, o);
    __shared__ float wsum[4];
    if ((tid & 63) == 0) wsum[tid >> 6] = sum;
    __syncthreads();
    if (tid == 0) partial[bid] = wsum[0] + wsum[1] + wsum[2] + wsum[3];
}

// Final reduction over 2048 partials in one 1024-thread block.
__global__ __launch_bounds__(1024) void closs_reduce(const float* __restrict__ partial,
                                                     float* __restrict__ out) {
    const float2* p2 = (const float2*)partial;    // 1024 float2s
    float2 v = p2[threadIdx.x];
    float s = v.x + v.y;
    for (int o = 32; o > 0; o >>= 1) s += __shfl_down(s, o);
    __shared__ float wsum[16];
    if ((threadIdx.x & 63) == 0) wsum[threadIdx.x >> 6] = s;
    __syncthreads();
    if (threadIdx.x == 0) {
        float t = 0.f;
#pragma unroll
        for (int i = 0; i < 16; ++i) t += wsum[i];
        out[0] = t * (1.0f / (float)NELEM);
    }
}

extern "C" void kernel_launch(void* const* d_in, const int* in_sizes, int n_in,
                              void* d_out, int out_size, void* d_ws, size_t ws_size,
                              hipStream_t stream) {
    const float* y_true = (const float*)d_in[0];
    const float* y_pred = (const float*)d_in[1];
    float* out = (float*)d_out;
    float* partial = (float*)d_ws;   // NBLK*4 = 8 KB scratch

    closs_main<<<NBLK, 256, 0, stream>>>(y_true, y_pred, partial);
    closs_reduce<<<1, 1024, 0, stream>>>(partial, out);
}

// Round 3
// 147.749 us; speedup vs baseline: 1.0654x; 1.0654x over previous
//
#include <hip/hip_runtime.h>

#define HH 1024
#define WW 1024
#define NB 16
#define TR 8                        // output rows per block (= staged rows)
#define NBLK (NB * (HH / TR))       // 2048 blocks
#define NELEM ((long long)NB * HH * WW)

// Build an 8-float stencil window [c0-2 .. c0+5] from an LDS row.
// Lane stride is 16 B -> 2 lanes/bank on all pieces = conflict-free (m136).
__device__ __forceinline__ void lds_win(const float* __restrict__ S, int row,
                                        int c0, bool ledge, bool redge, float w[8]) {
    const float* p = S + row * WW;
    float2 L = *(const float2*)(p + (ledge ? c0 : c0 - 2));
    float4 M = *(const float4*)(p + c0);
    float2 R = *(const float2*)(p + (redge ? c0 : c0 + 4));
    if (ledge) { L.x = 0.f; L.y = 0.f; }
    if (redge) { R.x = 0.f; R.y = 0.f; }
    w[0]=L.x; w[1]=L.y; w[2]=M.x; w[3]=M.y; w[4]=M.z; w[5]=M.w; w[6]=R.x; w[7]=R.y;
}

// Same window but directly from global (halo rows only: the neighbor block
// staged these lines, so they are L2/LLC-hot). Values and zero-fix order are
// bit-identical to the staged path; out-of-image rows are the zero pad.
__device__ __forceinline__ void gwin(const float* __restrict__ ybase, int gy,
                                     int c0, bool ledge, bool redge, float w[8]) {
    if (gy >= 0 && gy < HH) {                     // block-uniform branch
        const float* r = ybase + gy * WW;
        float2 L = *(const float2*)(r + (ledge ? c0 : c0 - 2));
        float4 M = *(const float4*)(r + c0);
        float2 R = *(const float2*)(r + (redge ? c0 : c0 + 4));
        if (ledge) { L.x = 0.f; L.y = 0.f; }
        if (redge) { R.x = 0.f; R.y = 0.f; }
        w[0]=L.x; w[1]=L.y; w[2]=M.x; w[3]=M.y; w[4]=M.z; w[5]=M.w; w[6]=R.x; w[7]=R.y;
    } else {
#pragma unroll
        for (int i = 0; i < 8; ++i) w[i] = 0.f;
    }
}

__global__ __launch_bounds__(256, 5) void closs_main(const float* __restrict__ yt,
                                                     const float* __restrict__ yp,
                                                     float* __restrict__ partial) {
    __shared__ float S[TR * WW];        // 32 KB -> 5 blocks/CU resident (was 48 KB/3)

    const int bid  = blockIdx.x;
    const int img  = bid >> 7;          // 128 tiles per image
    const int tile = bid & 127;
    const int y0   = tile * TR;
    const int tid  = threadIdx.x;
    const int c0   = tid << 2;          // 4 columns per thread

    const float* __restrict__ ybase = yp + (long long)img * (HH * WW);
    const float* __restrict__ tbase = yt + ((long long)img * HH + y0) * WW;

    // Stage ONLY the 8 owned rows: always in-bounds -> no row bounds check,
    // pure aligned float4 streams. Halo rows are read from global in the
    // compute loop (L2-resident; staged by the neighboring blocks).
#pragma unroll
    for (int i = 0; i < TR; ++i)
        *(float4*)&S[i * WW + c0] = *(const float4*)(ybase + (y0 + i) * WW + c0);
    __syncthreads();

    const bool ledge = (tid == 0);
    const bool redge = (tid == 255);

    float sum = 0.f;
#pragma unroll
    for (int k = 0; k < TR; ++k) {
        float A[8], B[8], C[8];         // rows y0+k-2, y0+k, y0+k+2
        if (k < 2)  gwin(ybase, y0 + k - 2, c0, ledge, redge, A);   // top halo
        else        lds_win(S, k - 2, c0, ledge, redge, A);
        lds_win(S, k, c0, ledge, redge, B);
        if (k >= TR - 2) gwin(ybase, y0 + k + 2, c0, ledge, redge, C); // bottom halo
        else             lds_win(S, k + 2, c0, ledge, redge, C);

        const float4 t4 = *(const float4*)(tbase + k * WW + c0);
        const float tt[4] = {t4.x, t4.y, t4.z, t4.w};

#pragma unroll
        for (int j = 0; j < 4; ++j) {
            const float c = B[j + 2];
            // max|c-nb| = max(max(nb)-c, c-min(nb)); bit-identical to the
            // |diff| chain (absmax 0.0 since R3); folds to v_max3/v_min3.
            const float mxA = fmaxf(fmaxf(A[j], A[j + 2]), A[j + 4]);
            const float mxB = fmaxf(B[j], B[j + 4]);
            const float mxC = fmaxf(fmaxf(C[j], C[j + 2]), C[j + 4]);
            const float mx  = fmaxf(fmaxf(mxA, mxB), mxC);
            const float mnA = fminf(fminf(A[j], A[j + 2]), A[j + 4]);
            const float mnB = fminf(B[j], B[j + 4]);
            const float mnC = fminf(fminf(C[j], C[j + 2]), C[j + 4]);
            const float mn  = fminf(fminf(mnA, mnB), mnC);
            const float w   = fmaxf(mx - c, c - mn);

            // log1p(-c) == log(1-c) exactly in fp32 for c in [0.5,1)
            // (Sterbenz); -100 clamp covers c -> 1 / c == 0.
            const float lp  = fmaxf(__logf(c), -100.f);
            const float l1p = fmaxf(__logf(1.f - c), -100.f);
            const float th  = (c >= 0.5f) ? c : 0.f;
            sum += w * th - l1p - tt[j] * (lp - l1p);
        }
    }

    // Block reduction -> one partial write (no atomics: R4 proved 16K
    // same-address atomicAdds serialize to ~215 us).
    for (int o = 32; o > 0; o >>= 1) sum += __shfl_down(sum, o);
    __shared__ float wsum[4];
    if ((tid & 63) == 0) wsum[tid >> 6] = sum;
    __syncthreads();
    if (tid == 0) partial[bid] = wsum[0] + wsum[1] + wsum[2] + wsum[3];
}

// Final reduction over 2048 partials in one 1024-thread block.
__global__ __launch_bounds__(1024) void closs_reduce(const float* __restrict__ partial,
                                                     float* __restrict__ out) {
    const float2* p2 = (const float2*)partial;    // 1024 float2s
    float2 v = p2[threadIdx.x];
    float s = v.x + v.y;
    for (int o = 32; o > 0; o >>= 1) s += __shfl_down(s, o);
    __shared__ float wsum[16];
    if ((threadIdx.x & 63) == 0) wsum[threadIdx.x >> 6] = s;
    __syncthreads();
    if (threadIdx.x == 0) {
        float t = 0.f;
#pragma unroll
        for (int i = 0; i < 16; ++i) t += wsum[i];
        out[0] = t * (1.0f / (float)NELEM);
    }
}

extern "C" void kernel_launch(void* const* d_in, const int* in_sizes, int n_in,
                              void* d_out, int out_size, void* d_ws, size_t ws_size,
                              hipStream_t stream) {
    const float* y_true = (const float*)d_in[0];
    const float* y_pred = (const float*)d_in[1];
    float* out = (float*)d_out;
    float* partial = (float*)d_ws;   // NBLK*4 = 8 KB scratch

    closs_main<<<NBLK, 256, 0, stream>>>(y_true, y_pred, partial);
    closs_reduce<<<1, 1024, 0, stream>>>(partial, out);
}